// Round 4
// baseline (860.059 us; speedup 1.0000x reference)
//
#include <hip/hip_runtime.h>
#include <hip/hip_bf16.h>
#include <hip/hip_cooperative_groups.h>

namespace cg = cooperative_groups;

#define Bb 64
#define Tt 20
#define Ee 512
#define Vv 32000

typedef __hip_bfloat16 bf16;
typedef __attribute__((ext_vector_type(8))) short bf16x8;
typedef __attribute__((ext_vector_type(4))) float f32x4;

__device__ __forceinline__ float bf2f(bf16 x) { return __bfloat162float(x); }
__device__ __forceinline__ bf16 f2bf(float x) { return __float2bfloat16(x); }

// ---------------------------------------------------------------------------
// Kernel 1: embedding gather (fp32 -> bf16).
// grid = B*T blocks, 128 threads (4 elements each).
//  - emb[b,t,:]  = bf16(W_emb[captions[b,t], :])
//  - seq[b,0,:]  = emb[b,0,:]
// ---------------------------------------------------------------------------
__global__ void embed_init(const int* __restrict__ caps, const float* __restrict__ Wemb,
                           bf16* __restrict__ emb, bf16* __restrict__ seq) {
  int row = blockIdx.x;            // b*T + t
  int t = row % Tt;
  int tid = threadIdx.x;           // 0..127
  int tok = caps[row];
  float4 v = ((const float4*)(Wemb + (size_t)tok * Ee))[tid];
  union { ushort4 u; bf16 h[4]; } pk;
  pk.h[0] = f2bf(v.x); pk.h[1] = f2bf(v.y); pk.h[2] = f2bf(v.z); pk.h[3] = f2bf(v.w);
  ((ushort4*)(emb + (size_t)row * Ee))[tid] = pk.u;
  if (t == 0) ((ushort4*)(seq + (size_t)row * Ee))[tid] = pk.u;   // row == b*T
}

// ---------------------------------------------------------------------------
// Kernel 2: PERSISTENT cooperative LSTM — all 19 steps in one launch.
// grid = 32 WGs x 256 thr (4 waves). WG w owns j-tile j0=w*16 (16 j x 4 gates).
// - Weight slices (W_ih,W_hh rows for this tile) staged fp32->bf16 into LDS
//   ONCE (128 rows x pitch 520 bf16 = 133,120 B; pitch 520 -> conflict-free
//   ds_read_b128: lane ln offset = ln*1040 B -> bank 4*(ln+q) spreads 8 groups).
// - Cell state c: 4 values/thread in REGISTERS for all 19 steps (thread p
//   owns (b,j) = (p>>4, p&15) in its tile; same mapping every step).
// - h round-trips through seq[] in global (only cross-WG data, 64 KB/step);
//   __threadfence + grid.sync between steps.
// - t=1 skips the h-MFMA entirely (h0 = 0).
// ---------------------------------------------------------------------------
#define WPITCH 520                              // 512 + 8 bf16 pad
#define WLDS_BYTES (128 * WPITCH * 2)           // 133120
#define GSM_OFF WLDS_BYTES
#define LSTM_LDS (WLDS_BYTES + 4 * 64 * 16 * 4) // + 16384 = 149504

extern __shared__ __align__(16) char smem_raw[];

__global__ __launch_bounds__(256, 1) void lstm_persist(
    const bf16* __restrict__ emb, bf16* __restrict__ seq,
    const float* __restrict__ feats,
    const float* __restrict__ Wih, const float* __restrict__ Whh,
    const float* __restrict__ bih, const float* __restrict__ bhh) {
  cg::grid_group grid = cg::this_grid();
  bf16* wlds = (bf16*)smem_raw;                       // [2*64][WPITCH]
  float* gsm = (float*)(smem_raw + GSM_OFF);          // [4][64][16]

  int tid = threadIdx.x;
  int lane = tid & 63;
  int q = lane >> 4, ln = lane & 15;
  int g = tid >> 6;                 // wave id == gate id (0=i,1=f,2=g,3=o)
  int j0 = blockIdx.x * 16;
  const long XS = (long)Tt * Ee;    // batch-row stride in emb/seq

  // ---- stage weight slices fp32 -> bf16 LDS (once) ----
  // LDS row r in [0,64): gate = r>>4, global row = (r>>4)*512 + j0 + (r&15)
#pragma unroll
  for (int mat = 0; mat < 2; ++mat) {
    const float* W = mat ? Whh : Wih;
    for (int idx = tid; idx < 64 * 128; idx += 256) {  // 64 rows x 128 float4-chunks
      int r = idx >> 7, c4 = (idx & 127) << 2;
      int grow = (r >> 4) * Ee + j0 + (r & 15);
      float4 v = *(const float4*)(W + (size_t)grow * Ee + c4);
      union { ushort4 u; bf16 h[4]; } pk;
      pk.h[0] = f2bf(v.x); pk.h[1] = f2bf(v.y); pk.h[2] = f2bf(v.z); pk.h[3] = f2bf(v.w);
      *(ushort4*)(wlds + (size_t)(mat * 64 + r) * WPITCH + c4) = pk.u;
    }
  }

  // ---- persistent per-thread pointwise state ----
  // thread handles points p = tid + it*256: b = p>>4, jl = p&15
  float cstate[4], bs_i[4], bs_f[4], bs_g[4], bs_o[4];
#pragma unroll
  for (int it = 0; it < 4; ++it) {
    int p = tid + it * 256;
    int b = p >> 4, jj = j0 + (p & 15);
    cstate[it] = feats[(size_t)b * Ee + jj];
    bs_i[it] = bih[jj]          + bhh[jj];
    bs_f[it] = bih[Ee + jj]     + bhh[Ee + jj];
    bs_g[it] = bih[2 * Ee + jj] + bhh[2 * Ee + jj];
    bs_o[it] = bih[3 * Ee + jj] + bhh[3 * Ee + jj];
  }
  __syncthreads();

  f32x4 zero = {0.f, 0.f, 0.f, 0.f};
  for (int t = 1; t < Tt; ++t) {
    f32x4 acc[4];
#pragma unroll
    for (int mt = 0; mt < 4; ++mt) acc[mt] = zero;

    // x @ W_ih^T   (x_t = emb[:, t-1])
    const bf16* xb = emb + (size_t)(t - 1) * Ee;
#pragma unroll 4
    for (int kk = 0; kk < 16; ++kk) {
      int k = kk * 32 + q * 8;
      bf16x8 bfrag = *(const bf16x8*)(wlds + (size_t)(g * 16 + ln) * WPITCH + k);
#pragma unroll
      for (int mt = 0; mt < 4; ++mt) {
        bf16x8 afrag = *(const bf16x8*)(xb + (size_t)(mt * 16 + ln) * XS + k);
        acc[mt] = __builtin_amdgcn_mfma_f32_16x16x32_bf16(afrag, bfrag, acc[mt], 0, 0, 0);
      }
    }
    // h @ W_hh^T   (h_{t-1} = seq[:, t-1]; skip at t=1, h0 = 0)
    if (t > 1) {
      const bf16* hb = seq + (size_t)(t - 1) * Ee;
#pragma unroll 4
      for (int kk = 0; kk < 16; ++kk) {
        int k = kk * 32 + q * 8;
        bf16x8 bfrag = *(const bf16x8*)(wlds + (size_t)(64 + g * 16 + ln) * WPITCH + k);
#pragma unroll
        for (int mt = 0; mt < 4; ++mt) {
          bf16x8 afrag = *(const bf16x8*)(hb + (size_t)(mt * 16 + ln) * XS + k);
          acc[mt] = __builtin_amdgcn_mfma_f32_16x16x32_bf16(afrag, bfrag, acc[mt], 0, 0, 0);
        }
      }
    }

    // gates -> LDS  (D layout: col=ln (j), row=q*4+r (b within mt))
#pragma unroll
    for (int mt = 0; mt < 4; ++mt)
#pragma unroll
      for (int r = 0; r < 4; ++r)
        gsm[((size_t)g * 64 + mt * 16 + q * 4 + r) * 16 + ln] = acc[mt][r];
    __syncthreads();

    // pointwise: 4 (b,j) points per thread, c in registers
#pragma unroll
    for (int it = 0; it < 4; ++it) {
      int p = tid + it * 256;
      int b = p >> 4, jl = p & 15;
      float iv = gsm[(0 * 64 + b) * 16 + jl] + bs_i[it];
      float fv = gsm[(1 * 64 + b) * 16 + jl] + bs_f[it];
      float gv = gsm[(2 * 64 + b) * 16 + jl] + bs_g[it];
      float ov = gsm[(3 * 64 + b) * 16 + jl] + bs_o[it];
      iv = 1.f / (1.f + __expf(-iv));
      fv = 1.f / (1.f + __expf(-fv));
      ov = 1.f / (1.f + __expf(-ov));
      gv = 1.f - 2.f / (__expf(2.f * gv) + 1.f);        // tanh
      float cv = fv * cstate[it] + iv * gv;
      cstate[it] = cv;
      float hv = ov * (1.f - 2.f / (__expf(2.f * cv) + 1.f));
      seq[((size_t)b * Tt + t) * Ee + j0 + jl] = f2bf(hv);
    }
    __threadfence();
    grid.sync();   // h_t visible grid-wide; also orders gsm reuse
  }
}

// ---------------------------------------------------------------------------
// Kernel 3: logits = seq[1280,512](bf16) @ W_out[32000,512](fp32)^T + b_out.
// 128x128 tile, BK=64, register staging, inline fp32->bf16 of W_out.
// GRID SWIZZLE: blockIdx.x = m (10, fastest) so the 10 m-blocks sharing a
// W_out slice run concurrently -> W fetched ~once from HBM (was 5x).
// ---------------------------------------------------------------------------
#define BM 128
#define BN 128
#define BK 64

__global__ __launch_bounds__(256) void out_gemm(const bf16* __restrict__ A,    // [1280,512] bf16
                                                const float* __restrict__ Bw,  // [32000,512] fp32
                                                const float* __restrict__ bias,
                                                float* __restrict__ Cb) {
  __shared__ __align__(16) bf16 As[BM * BK];   // 16 KB
  __shared__ __align__(16) bf16 Bs[BN * BK];   // 16 KB
  int tid = threadIdx.x;
  int lane = tid & 63;
  int quad = lane >> 4, ln = lane & 15;
  int wid = tid >> 6;
  int wm = wid & 1, wn = wid >> 1;
  int m0 = blockIdx.x * BM, n0 = blockIdx.y * BN;   // m fastest

  f32x4 zero = {0.f, 0.f, 0.f, 0.f};
  f32x4 acc[4][4];
#pragma unroll
  for (int mt = 0; mt < 4; ++mt)
#pragma unroll
    for (int nt = 0; nt < 4; ++nt) acc[mt][nt] = zero;

  for (int k0 = 0; k0 < Ee; k0 += BK) {
    uint4 avv[4];
    float4 bf0[4], bf1[4];
#pragma unroll
    for (int q = 0; q < 4; ++q) {
      int fb = (q * 256 + tid) * 16;   // byte offset within bf16 tile
      int row = fb >> 7;               // 128 B per row (64 bf16)
      int c8 = (fb & 127) >> 1;        // bf16 column start
      avv[q] = *(const uint4*)((const char*)A + ((size_t)(m0 + row) * Ee + k0) * 2 + (fb & 127));
      const float* src = Bw + (size_t)(n0 + row) * Ee + k0 + c8;
      bf0[q] = *(const float4*)(src);
      bf1[q] = *(const float4*)(src + 4);
    }
#pragma unroll
    for (int q = 0; q < 4; ++q) {
      int fb = (q * 256 + tid) * 16;
      *(uint4*)((char*)As + fb) = avv[q];
      union { uint4 u; bf16 h[8]; } pk;
      pk.h[0] = f2bf(bf0[q].x); pk.h[1] = f2bf(bf0[q].y);
      pk.h[2] = f2bf(bf0[q].z); pk.h[3] = f2bf(bf0[q].w);
      pk.h[4] = f2bf(bf1[q].x); pk.h[5] = f2bf(bf1[q].y);
      pk.h[6] = f2bf(bf1[q].z); pk.h[7] = f2bf(bf1[q].w);
      *(uint4*)((char*)Bs + fb) = pk.u;
    }
    __syncthreads();

#pragma unroll
    for (int kk = 0; kk < 2; ++kk) {
      int kb = (kk * 32 + quad * 8) * 2;
      bf16x8 af[4], bfv[4];
#pragma unroll
      for (int mt = 0; mt < 4; ++mt)
        af[mt] = *(const bf16x8*)((const char*)As + (wm * 64 + mt * 16 + ln) * 128 + kb);
#pragma unroll
      for (int nt = 0; nt < 4; ++nt)
        bfv[nt] = *(const bf16x8*)((const char*)Bs + (wn * 64 + nt * 16 + ln) * 128 + kb);
#pragma unroll
      for (int mt = 0; mt < 4; ++mt)
#pragma unroll
        for (int nt = 0; nt < 4; ++nt)
          acc[mt][nt] = __builtin_amdgcn_mfma_f32_16x16x32_bf16(af[mt], bfv[nt], acc[mt][nt], 0, 0, 0);
    }
    __syncthreads();
  }

  // epilogue: + bias, fp32 store. D: col = lane&15, row = quad*4 + reg.
  float bv[4];
#pragma unroll
  for (int nt = 0; nt < 4; ++nt)
    bv[nt] = bias[n0 + wn * 64 + nt * 16 + ln];
#pragma unroll
  for (int mt = 0; mt < 4; ++mt) {
#pragma unroll
    for (int nt = 0; nt < 4; ++nt) {
      int col = n0 + wn * 64 + nt * 16 + ln;
#pragma unroll
      for (int r = 0; r < 4; ++r) {
        int row = m0 + wm * 64 + mt * 16 + quad * 4 + r;
        Cb[(size_t)row * Vv + col] = acc[mt][nt][r] + bv[nt];
      }
    }
  }
}

// ---------------------------------------------------------------------------
extern "C" void kernel_launch(void* const* d_in, const int* in_sizes, int n_in,
                              void* d_out, int out_size, void* d_ws, size_t ws_size,
                              hipStream_t stream) {
  (void)in_sizes; (void)n_in; (void)out_size; (void)ws_size;
  const float* feats = (const float*)d_in[0];
  const int*   caps  = (const int*)d_in[1];
  const float* Wemb  = (const float*)d_in[2];
  const float* Wout  = (const float*)d_in[3];
  const float* bout  = (const float*)d_in[4];
  const float* Wih   = (const float*)d_in[5];
  const float* Whh   = (const float*)d_in[6];
  const float* bih   = (const float*)d_in[7];
  const float* bhh   = (const float*)d_in[8];
  float* out = (float*)d_out;

  // workspace: emb [B,T,E] bf16 + seq [B,T,E] bf16  (~2.6 MB)
  bf16* emb = (bf16*)d_ws;
  bf16* seq = emb + (size_t)Bb * Tt * Ee;

  embed_init<<<Bb * Tt, 128, 0, stream>>>(caps, Wemb, emb, seq);

  hipFuncSetAttribute((const void*)lstm_persist,
                      hipFuncAttributeMaxDynamicSharedMemorySize, LSTM_LDS);
  const bf16* emb_c = emb;
  bf16* seq_p = seq;
  void* args[] = {(void*)&emb_c, (void*)&seq_p, (void*)&feats,
                  (void*)&Wih, (void*)&Whh, (void*)&bih, (void*)&bhh};
  hipLaunchCooperativeKernel((void*)lstm_persist, dim3(32), dim3(256),
                             args, LSTM_LDS, stream);

  dim3 grid((Bb * Tt) / BM, Vv / BN);   // 10 x 250, m fastest
  out_gemm<<<grid, 256, 0, stream>>>(seq, Wout, bout, out);
}